// Round 1
// baseline (431.382 us; speedup 1.0000x reference)
//
#include <hip/hip_runtime.h>

typedef short bf16x8 __attribute__((ext_vector_type(8)));      // 8 bf16 in 4 VGPRs
typedef float f32x4 __attribute__((ext_vector_type(4)));
typedef unsigned short ushort4v __attribute__((ext_vector_type(4)));
typedef unsigned short ushort8 __attribute__((ext_vector_type(8)));

#define DEVI static __device__ __forceinline__

DEVI unsigned short f2bf(float f) {               // RTNE fp32 -> bf16
    unsigned u = __float_as_uint(f);
    u += 0x7FFFu + ((u >> 16) & 1u);
    return (unsigned short)(u >> 16);
}
DEVI float b2f(unsigned short s) { return __uint_as_float(((unsigned)s) << 16); }

typedef __attribute__((address_space(3))) unsigned int* lds_ptr_t;
typedef const __attribute__((address_space(1))) unsigned int* gbl_ptr_t;
#define GLDS(gp, lp) __builtin_amdgcn_global_load_lds((gbl_ptr_t)(gp), (lds_ptr_t)(lp), 16, 0, 0)

// ---------------- fp32 -> bf16 convert (n multiple of 4) ----------------
__global__ void cvt_kernel(const float* __restrict__ src, unsigned short* __restrict__ dst, int n) {
    int i = (blockIdx.x * 256 + threadIdx.x) * 4;
    if (i >= n) return;
    float4 v = *(const float4*)(src + i);
    ushort4v o;
    o.x = f2bf(v.x); o.y = f2bf(v.y); o.z = f2bf(v.z); o.w = f2bf(v.w);
    *(ushort4v*)(dst + i) = o;
}

// ---------------- bf16 GEMM, C[m][n] = sum_k A[m][k]*W[n][k] + bias[n] ----------------
// M=4096, N=1024, K=1024 fixed. MODE 0: bf16 out [B,NH,S,HD]; MODE 1: fp32 out [M,N];
// MODE 2: bf16 out transposed per head [B,NH,HD,S].
template <int MODE>
__global__ __launch_bounds__(256) void gemm_bt(const unsigned short* __restrict__ A,
                                               const unsigned short* __restrict__ Bw,
                                               const float* __restrict__ bias,
                                               void* __restrict__ Cout) {
    constexpr int K = 1024;
    __shared__ unsigned short As[128 * 32];
    __shared__ unsigned short Bs[128 * 32];
    const int t = threadIdx.x;
    const int w = t >> 6, l = t & 63;
    const int wr = w >> 1, wc = w & 1;
    const int fr = l & 15, fg = l >> 4;
    const int m0 = blockIdx.y * 128, n0 = blockIdx.x * 128;

    f32x4 acc[4][4] = {};

    const int c0 = t, c1 = 256 + t;
    const int r0 = c0 >> 2, q0off = (c0 & 3) * 8;
    const int r1 = c1 >> 2, q1off = (c1 & 3) * 8;

    for (int kb = 0; kb < K; kb += 32) {
        GLDS(A + (size_t)(m0 + r0) * K + kb + q0off, As + c0 * 8);
        GLDS(A + (size_t)(m0 + r1) * K + kb + q1off, As + c1 * 8);
        GLDS(Bw + (size_t)(n0 + r0) * K + kb + q0off, Bs + c0 * 8);
        GLDS(Bw + (size_t)(n0 + r1) * K + kb + q1off, Bs + c1 * 8);
        asm volatile("s_waitcnt vmcnt(0)" ::: "memory");
        __syncthreads();
        bf16x8 af[4], bfv[4];
#pragma unroll
        for (int mi = 0; mi < 4; mi++)
            af[mi] = *(const bf16x8*)(As + (wr * 64 + mi * 16 + fr) * 32 + fg * 8);
#pragma unroll
        for (int ni = 0; ni < 4; ni++)
            bfv[ni] = *(const bf16x8*)(Bs + (wc * 64 + ni * 16 + fr) * 32 + fg * 8);
#pragma unroll
        for (int mi = 0; mi < 4; mi++)
#pragma unroll
            for (int ni = 0; ni < 4; ni++)
                acc[mi][ni] = __builtin_amdgcn_mfma_f32_16x16x32_bf16(af[mi], bfv[ni], acc[mi][ni], 0, 0, 0);
        __syncthreads();
    }

    // Epilogue. D layout (m89-verified): col = lane&15, row = (lane>>4)*4 + r
#pragma unroll
    for (int ni = 0; ni < 4; ni++) {
        const int n = n0 + wc * 64 + ni * 16 + fr;
        const float bv = bias[n];
#pragma unroll
        for (int mi = 0; mi < 4; mi++) {
            const int mb = m0 + wr * 64 + mi * 16 + fg * 4;
            if constexpr (MODE == 1) {
                float* C = (float*)Cout;
#pragma unroll
                for (int r = 0; r < 4; r++) C[(size_t)(mb + r) * 1024 + n] = acc[mi][ni][r] + bv;
            } else if constexpr (MODE == 0) {
                unsigned short* C = (unsigned short*)Cout;
                const int h = n >> 6, hd = n & 63;
#pragma unroll
                for (int r = 0; r < 4; r++) {
                    const int m = mb + r;
                    const int bb = m >> 11, s = m & 2047;
                    C[(size_t)((bb * 16 + h) * 2048 + s) * 64 + hd] = f2bf(acc[mi][ni][r] + bv);
                }
            } else {  // MODE 2: vt[B,NH,HD,S]; 4 consecutive s per lane -> 8B packed store
                unsigned short* C = (unsigned short*)Cout;
                const int h = n >> 6, hd = n & 63;
                const int bb = mb >> 11, s = mb & 2047;
                ushort4v pk;
                pk.x = f2bf(acc[mi][ni][0] + bv);
                pk.y = f2bf(acc[mi][ni][1] + bv);
                pk.z = f2bf(acc[mi][ni][2] + bv);
                pk.w = f2bf(acc[mi][ni][3] + bv);
                *(ushort4v*)(C + (size_t)((bb * 16 + h) * 64 + hd) * 2048 + s) = pk;
            }
        }
    }
}

// ---------------- fused attention ----------------
// Block = 32 query rows of one (b,h). 256 threads = 4 waves.
// Wave w owns key-range [w*512, w*512+512) for both QK^T and PV (k-split).
__global__ __launch_bounds__(256) void attn_kernel(const unsigned short* __restrict__ Qh,  // [B*NH,S,64]
                                                   const unsigned short* __restrict__ Kh,  // [B*NH,S,64]
                                                   const unsigned short* __restrict__ Vt,  // [B*NH,64,S]
                                                   unsigned short* __restrict__ Obuf,      // [B*S,1024] bf16
                                                   float* __restrict__ AttnOut) {          // [B*NH,S,S] fp32
    __shared__ unsigned short P[32 * 2048];  // 128 KB, XOR-swizzled rows
    __shared__ float ored[32][68];
    __shared__ float rpart[32][4];
    __shared__ float rinv[32];

    const int qt = blockIdx.x, h = blockIdx.y, b = blockIdx.z;
    const int bh = b * 16 + h;
    const int q0 = qt * 32;
    const int t = threadIdx.x, w = t >> 6, l = t & 63;
    const int fr = l & 15, fg = l >> 4;
    const int nbase = w * 512;

    for (int i = t; i < 32 * 68; i += 256) (&ored[0][0])[i] = 0.0f;

    // Q fragments (A operand): row = lane&15, k = 8*(lane>>4)+j
    const unsigned short* qb = Qh + (size_t)(bh * 2048 + q0) * 64;
    bf16x8 qf[2][2];
#pragma unroll
    for (int mt = 0; mt < 2; mt++)
#pragma unroll
        for (int ks = 0; ks < 2; ks++)
            qf[mt][ks] = *(const bf16x8*)(qb + (size_t)(mt * 16 + fr) * 64 + ks * 32 + fg * 8);

    // ---- QK^T + exp + P store + row-sum ----
    const unsigned short* kbase = Kh + (size_t)bh * 2048 * 64;
    float rs[2][4] = {};
#pragma unroll 2
    for (int nt = 0; nt < 32; nt++) {
        const int n0c = nbase + nt * 16;
        const unsigned short* kr = kbase + (size_t)(n0c + fr) * 64 + fg * 8;
        bf16x8 kf0 = *(const bf16x8*)(kr);
        bf16x8 kf1 = *(const bf16x8*)(kr + 32);
#pragma unroll
        for (int mt = 0; mt < 2; mt++) {
            f32x4 d = {};
            d = __builtin_amdgcn_mfma_f32_16x16x32_bf16(qf[mt][0], kf0, d, 0, 0, 0);
            d = __builtin_amdgcn_mfma_f32_16x16x32_bf16(qf[mt][1], kf1, d, 0, 0, 0);
#pragma unroll
            for (int r = 0; r < 4; r++) {
                const float p = __expf(d[r] * 0.125f);  // no max-sub: |score| << 88, fp32-safe
                rs[mt][r] += p;
                const int row = mt * 16 + fg * 4 + r;
                const unsigned off = (unsigned)(row * 4096 + (n0c + fr) * 2) ^ (unsigned)((row & 7) << 4);
                *(unsigned short*)((char*)P + off) = f2bf(p);
            }
        }
    }
    // reduce row-sums over the 16 column-lanes (same rows within each lane-group)
#pragma unroll
    for (int mask = 1; mask < 16; mask <<= 1)
#pragma unroll
        for (int mt = 0; mt < 2; mt++)
#pragma unroll
            for (int r = 0; r < 4; r++) rs[mt][r] += __shfl_xor(rs[mt][r], mask, 64);
    if (fr == 0) {
#pragma unroll
        for (int mt = 0; mt < 2; mt++)
#pragma unroll
            for (int r = 0; r < 4; r++) rpart[mt * 16 + fg * 4 + r][w] = rs[mt][r];
    }
    __syncthreads();
    if (t < 32) rinv[t] = 1.0f / (rpart[t][0] + rpart[t][1] + rpart[t][2] + rpart[t][3]);
    __syncthreads();

    // ---- attn global write (the 536MB stream) — issue early so it drains under PV ----
    {
        const int row = t >> 3, j = t & 7;
        const float ri = rinv[row];
        float* arow = AttnOut + (size_t)(bh * 2048 + q0 + row) * 2048;
#pragma unroll 4
        for (int i = 0; i < 32; i++) {
            const int col = i * 64 + j * 8;
            const unsigned off = (unsigned)(row * 4096 + col * 2) ^ (unsigned)((row & 7) << 4);
            const bf16x8 v = *(const bf16x8*)((const char*)P + off);
            float4 o0, o1;
            o0.x = b2f((unsigned short)v[0]) * ri;
            o0.y = b2f((unsigned short)v[1]) * ri;
            o0.z = b2f((unsigned short)v[2]) * ri;
            o0.w = b2f((unsigned short)v[3]) * ri;
            o1.x = b2f((unsigned short)v[4]) * ri;
            o1.y = b2f((unsigned short)v[5]) * ri;
            o1.z = b2f((unsigned short)v[6]) * ri;
            o1.w = b2f((unsigned short)v[7]) * ri;
            *(float4*)(arow + col) = o0;
            *(float4*)(arow + col + 4) = o1;
        }
    }

    // ---- PV: O += P[:, krange] @ V[krange, :] per wave ----
    f32x4 opv[2][4] = {};
    const unsigned short* vtb = Vt + (size_t)bh * 64 * 2048;
#pragma unroll 2
    for (int kt = 0; kt < 16; kt++) {
        const int kk = nbase + kt * 32;
        bf16x8 pa[2];
#pragma unroll
        for (int mt = 0; mt < 2; mt++) {
            const int row = mt * 16 + fr;
            const unsigned off = (unsigned)(row * 4096 + (kk + fg * 8) * 2) ^ (unsigned)((row & 7) << 4);
            pa[mt] = *(const bf16x8*)((const char*)P + off);
        }
#pragma unroll
        for (int nt = 0; nt < 4; nt++) {
            bf16x8 vf = *(const bf16x8*)(vtb + (size_t)(nt * 16 + fr) * 2048 + kk + fg * 8);
            opv[0][nt] = __builtin_amdgcn_mfma_f32_16x16x32_bf16(pa[0], vf, opv[0][nt], 0, 0, 0);
            opv[1][nt] = __builtin_amdgcn_mfma_f32_16x16x32_bf16(pa[1], vf, opv[1][nt], 0, 0, 0);
        }
    }
    // cross-wave O reduction (deterministic sequential adds)
    for (int ww = 0; ww < 4; ww++) {
        if (w == ww) {
#pragma unroll
            for (int mt = 0; mt < 2; mt++)
#pragma unroll
                for (int nt = 0; nt < 4; nt++)
#pragma unroll
                    for (int r = 0; r < 4; r++)
                        ored[mt * 16 + fg * 4 + r][nt * 16 + fr] += opv[mt][nt][r];
        }
        __syncthreads();
    }
    // normalized O -> Obuf bf16 [B*S, 1024]
    {
        const int row = t >> 3, cb = (t & 7) * 8;
        const float ri = rinv[row];
        ushort8 pk;
#pragma unroll
        for (int j = 0; j < 8; j++) pk[j] = f2bf(ored[row][cb + j] * ri);
        *(ushort8*)(Obuf + (size_t)(b * 2048 + q0 + row) * 1024 + h * 64 + cb) = pk;
    }
}

extern "C" void kernel_launch(void* const* d_in, const int* in_sizes, int n_in,
                              void* d_out, int out_size, void* d_ws, size_t ws_size,
                              hipStream_t stream) {
    const float* q = (const float*)d_in[0];
    const float* k = (const float*)d_in[1];
    const float* v = (const float*)d_in[2];
    const float* wqw = (const float*)d_in[3];
    const float* wqb = (const float*)d_in[4];
    const float* wkw = (const float*)d_in[5];
    const float* wkb = (const float*)d_in[6];
    const float* wvw = (const float*)d_in[7];
    const float* wvb = (const float*)d_in[8];
    const float* wow = (const float*)d_in[9];
    const float* wob = (const float*)d_in[10];

    char* ws = (char*)d_ws;
    unsigned short* xbf  = (unsigned short*)(ws);              // 8 MB staging (reused q,k,v)
    unsigned short* wbf  = (unsigned short*)(ws + 8388608);    // 2 MB weight staging (reused)
    unsigned short* qh   = (unsigned short*)(ws + 10485760);   // [B,NH,S,HD] bf16
    unsigned short* kh   = (unsigned short*)(ws + 18874368);   // [B,NH,S,HD] bf16
    unsigned short* vt   = (unsigned short*)(ws + 27262976);   // [B,NH,HD,S] bf16
    unsigned short* obuf = (unsigned short*)(ws + 35651584);   // [B*S,H] bf16

    float* finalOut = (float*)d_out;
    float* attnOut = finalOut + 4194304;

    const int NX = 4194304, NW = 1048576;
    dim3 gGrid(8, 32), aGrid(64, 16, 2);

    cvt_kernel<<<NX / 1024, 256, 0, stream>>>(q, xbf, NX);
    cvt_kernel<<<NW / 1024, 256, 0, stream>>>(wqw, wbf, NW);
    gemm_bt<0><<<gGrid, 256, 0, stream>>>(xbf, wbf, wqb, qh);

    cvt_kernel<<<NX / 1024, 256, 0, stream>>>(k, xbf, NX);
    cvt_kernel<<<NW / 1024, 256, 0, stream>>>(wkw, wbf, NW);
    gemm_bt<0><<<gGrid, 256, 0, stream>>>(xbf, wbf, wkb, kh);

    cvt_kernel<<<NX / 1024, 256, 0, stream>>>(v, xbf, NX);
    cvt_kernel<<<NW / 1024, 256, 0, stream>>>(wvw, wbf, NW);
    gemm_bt<2><<<gGrid, 256, 0, stream>>>(xbf, wbf, wvb, vt);

    attn_kernel<<<aGrid, 256, 0, stream>>>(qh, kh, vt, obuf, attnOut);

    cvt_kernel<<<NW / 1024, 256, 0, stream>>>(wow, wbf, NW);
    gemm_bt<1><<<gGrid, 256, 0, stream>>>(obuf, wbf, wob, finalOut);
}

// Round 2
// 343.042 us; speedup vs baseline: 1.2575x; 1.2575x over previous
//
#include <hip/hip_runtime.h>

typedef short bf16x8 __attribute__((ext_vector_type(8)));      // 8 bf16 in 4 VGPRs
typedef float f32x4 __attribute__((ext_vector_type(4)));
typedef unsigned short ushort4v __attribute__((ext_vector_type(4)));
typedef unsigned short ushort8 __attribute__((ext_vector_type(8)));

#define DEVI static __device__ __forceinline__

DEVI unsigned short f2bf(float f) {               // RTNE fp32 -> bf16
    unsigned u = __float_as_uint(f);
    u += 0x7FFFu + ((u >> 16) & 1u);
    return (unsigned short)(u >> 16);
}
DEVI float b2f(unsigned short s) { return __uint_as_float(((unsigned)s) << 16); }

typedef __attribute__((address_space(3))) unsigned int* lds_ptr_t;
typedef const __attribute__((address_space(1))) unsigned int* gbl_ptr_t;
#define GLDS(gp, lp) __builtin_amdgcn_global_load_lds((gbl_ptr_t)(gp), (lds_ptr_t)(lp), 16, 0, 0)

// ---------------- fp32 -> bf16 convert (n multiple of 4) ----------------
__global__ void cvt_kernel(const float* __restrict__ src, unsigned short* __restrict__ dst, int n) {
    int i = (blockIdx.x * 256 + threadIdx.x) * 4;
    if (i >= n) return;
    float4 v = *(const float4*)(src + i);
    ushort4v o;
    o.x = f2bf(v.x); o.y = f2bf(v.y); o.z = f2bf(v.z); o.w = f2bf(v.w);
    *(ushort4v*)(dst + i) = o;
}

// ---------------- bf16 GEMM, C[m][n] = sum_k A[m][k]*W[n][k] + bias[n] ----------------
template <int MODE>
__global__ __launch_bounds__(256) void gemm_bt(const unsigned short* __restrict__ A,
                                               const unsigned short* __restrict__ Bw,
                                               const float* __restrict__ bias,
                                               void* __restrict__ Cout) {
    constexpr int K = 1024;
    __shared__ unsigned short As[128 * 32];
    __shared__ unsigned short Bs[128 * 32];
    const int t = threadIdx.x;
    const int w = t >> 6, l = t & 63;
    const int wr = w >> 1, wc = w & 1;
    const int fr = l & 15, fg = l >> 4;
    const int m0 = blockIdx.y * 128, n0 = blockIdx.x * 128;

    f32x4 acc[4][4] = {};

    const int c0 = t, c1 = 256 + t;
    const int r0 = c0 >> 2, q0off = (c0 & 3) * 8;
    const int r1 = c1 >> 2, q1off = (c1 & 3) * 8;

    for (int kb = 0; kb < K; kb += 32) {
        GLDS(A + (size_t)(m0 + r0) * K + kb + q0off, As + c0 * 8);
        GLDS(A + (size_t)(m0 + r1) * K + kb + q1off, As + c1 * 8);
        GLDS(Bw + (size_t)(n0 + r0) * K + kb + q0off, Bs + c0 * 8);
        GLDS(Bw + (size_t)(n0 + r1) * K + kb + q1off, Bs + c1 * 8);
        asm volatile("s_waitcnt vmcnt(0)" ::: "memory");
        __syncthreads();
        bf16x8 af[4], bfv[4];
#pragma unroll
        for (int mi = 0; mi < 4; mi++)
            af[mi] = *(const bf16x8*)(As + (wr * 64 + mi * 16 + fr) * 32 + fg * 8);
#pragma unroll
        for (int ni = 0; ni < 4; ni++)
            bfv[ni] = *(const bf16x8*)(Bs + (wc * 64 + ni * 16 + fr) * 32 + fg * 8);
#pragma unroll
        for (int mi = 0; mi < 4; mi++)
#pragma unroll
            for (int ni = 0; ni < 4; ni++)
                acc[mi][ni] = __builtin_amdgcn_mfma_f32_16x16x32_bf16(af[mi], bfv[ni], acc[mi][ni], 0, 0, 0);
        __syncthreads();
    }

#pragma unroll
    for (int ni = 0; ni < 4; ni++) {
        const int n = n0 + wc * 64 + ni * 16 + fr;
        const float bv = bias[n];
#pragma unroll
        for (int mi = 0; mi < 4; mi++) {
            const int mb = m0 + wr * 64 + mi * 16 + fg * 4;
            if constexpr (MODE == 1) {
                float* C = (float*)Cout;
#pragma unroll
                for (int r = 0; r < 4; r++) C[(size_t)(mb + r) * 1024 + n] = acc[mi][ni][r] + bv;
            } else if constexpr (MODE == 0) {
                unsigned short* C = (unsigned short*)Cout;
                const int h = n >> 6, hd = n & 63;
#pragma unroll
                for (int r = 0; r < 4; r++) {
                    const int m = mb + r;
                    const int bb = m >> 11, s = m & 2047;
                    C[(size_t)((bb * 16 + h) * 2048 + s) * 64 + hd] = f2bf(acc[mi][ni][r] + bv);
                }
            } else {
                unsigned short* C = (unsigned short*)Cout;
                const int h = n >> 6, hd = n & 63;
                const int bb = mb >> 11, s = mb & 2047;
                ushort4v pk;
                pk.x = f2bf(acc[mi][ni][0] + bv);
                pk.y = f2bf(acc[mi][ni][1] + bv);
                pk.z = f2bf(acc[mi][ni][2] + bv);
                pk.w = f2bf(acc[mi][ni][3] + bv);
                *(ushort4v*)(C + (size_t)((bb * 16 + h) * 64 + hd) * 2048 + s) = pk;
            }
        }
    }
}

// ---------------- fused attention v2: two-pass, swapped QK^T, reg->global attn ----------------
__global__ __launch_bounds__(256, 4) void attn_kernel(const unsigned short* __restrict__ Qh,
                                                      const unsigned short* __restrict__ Kh,
                                                      const unsigned short* __restrict__ Vt,
                                                      unsigned short* __restrict__ Obuf,
                                                      float* __restrict__ AttnOut) {
    __shared__ unsigned short Plds[16384];  // 32KB: per-wave 2x 4KB ping-pong P tiles [32q][64k] swizzled
    __shared__ float rpart[32][4];
    __shared__ float rinv_s[32];

    const int qt = blockIdx.x, h = blockIdx.y, b = blockIdx.z;
    const int bh = b * 16 + h;
    const int q0 = qt * 32;
    const int t = threadIdx.x, w = t >> 6, l = t & 63;
    const int fr = l & 15, fg = l >> 4;
    const unsigned swz = (unsigned)((fr & 7) << 4);

    const unsigned short* qb = Qh + (size_t)(bh * 2048 + q0) * 64;
    bf16x8 qf[2][2];
#pragma unroll
    for (int qs = 0; qs < 2; qs++)
#pragma unroll
        for (int kc = 0; kc < 2; kc++)
            qf[qs][kc] = *(const bf16x8*)(qb + (size_t)(qs * 16 + fr) * 64 + kc * 32 + fg * 8);

    const unsigned short* kbase = Kh + (size_t)bh * 2048 * 64;
    const unsigned short* vtb = Vt + (size_t)bh * 64 * 2048;

    // ---- Pass A: row-sums ----
    float s0 = 0.f, s1 = 0.f;
    for (int kt = 0; kt < 8; ++kt) {
        const int kb = w * 512 + kt * 64;
#pragma unroll
        for (int mt = 0; mt < 4; ++mt) {
            const unsigned short* kr = kbase + (size_t)(kb + mt * 16 + fr) * 64 + fg * 8;
            bf16x8 kf0 = *(const bf16x8*)kr;
            bf16x8 kf1 = *(const bf16x8*)(kr + 32);
            f32x4 d0 = {}, d1 = {};
            d0 = __builtin_amdgcn_mfma_f32_16x16x32_bf16(kf0, qf[0][0], d0, 0, 0, 0);
            d0 = __builtin_amdgcn_mfma_f32_16x16x32_bf16(kf1, qf[0][1], d0, 0, 0, 0);
            d1 = __builtin_amdgcn_mfma_f32_16x16x32_bf16(kf0, qf[1][0], d1, 0, 0, 0);
            d1 = __builtin_amdgcn_mfma_f32_16x16x32_bf16(kf1, qf[1][1], d1, 0, 0, 0);
#pragma unroll
            for (int r = 0; r < 4; r++) {
                s0 += __expf(d0[r] * 0.125f);
                s1 += __expf(d1[r] * 0.125f);
            }
        }
    }
    s0 += __shfl_xor(s0, 16, 64); s0 += __shfl_xor(s0, 32, 64);
    s1 += __shfl_xor(s1, 16, 64); s1 += __shfl_xor(s1, 32, 64);
    if (l < 16) { rpart[l][w] = s0; rpart[l + 16][w] = s1; }
    __syncthreads();
    if (t < 32) rinv_s[t] = 1.0f / (rpart[t][0] + rpart[t][1] + rpart[t][2] + rpart[t][3]);
    __syncthreads();
    const float ri0 = rinv_s[fr], ri1 = rinv_s[16 + fr];

    // ---- Pass B ----
    f32x4 opv[2][4] = {};
    float* attnB = AttnOut + (size_t)bh * 2048 * 2048;

    for (int kt = 0; kt < 8; ++kt) {
        const int kb = w * 512 + kt * 64;
        const unsigned pbase = (unsigned)((w * 2 + (kt & 1)) * 4096);
#pragma unroll
        for (int mt = 0; mt < 4; ++mt) {
            const unsigned short* kr = kbase + (size_t)(kb + mt * 16 + fr) * 64 + fg * 8;
            bf16x8 kf0 = *(const bf16x8*)kr;
            bf16x8 kf1 = *(const bf16x8*)(kr + 32);
            f32x4 d0 = {}, d1 = {};
            d0 = __builtin_amdgcn_mfma_f32_16x16x32_bf16(kf0, qf[0][0], d0, 0, 0, 0);
            d0 = __builtin_amdgcn_mfma_f32_16x16x32_bf16(kf1, qf[0][1], d0, 0, 0, 0);
            d1 = __builtin_amdgcn_mfma_f32_16x16x32_bf16(kf0, qf[1][0], d1, 0, 0, 0);
            d1 = __builtin_amdgcn_mfma_f32_16x16x32_bf16(kf1, qf[1][1], d1, 0, 0, 0);
            f32x4 p0, p1;
#pragma unroll
            for (int r = 0; r < 4; r++) {
                p0[r] = __expf(d0[r] * 0.125f) * ri0;
                p1[r] = __expf(d1[r] * 0.125f) * ri1;
            }
            const int kcol = kb + mt * 16 + fg * 4;
            __builtin_nontemporal_store(p0, (f32x4*)(attnB + (size_t)(q0 + fr) * 2048 + kcol));
            __builtin_nontemporal_store(p1, (f32x4*)(attnB + (size_t)(q0 + 16 + fr) * 2048 + kcol));
            ushort4v pk0, pk1;
#pragma unroll
            for (int r = 0; r < 4; r++) { pk0[r] = f2bf(p0[r]); pk1[r] = f2bf(p1[r]); }
            const unsigned colb = (unsigned)(mt * 32 + fg * 8) ^ swz;
            *(ushort4v*)((char*)Plds + pbase + (unsigned)fr * 128 + colb) = pk0;
            *(ushort4v*)((char*)Plds + pbase + (unsigned)(16 + fr) * 128 + colb) = pk1;
        }
        asm volatile("s_waitcnt lgkmcnt(0)" ::: "memory");
        __builtin_amdgcn_sched_barrier(0);
#pragma unroll
        for (int kc = 0; kc < 2; ++kc) {
            const unsigned ro = (unsigned)(kc * 64 + fg * 16) ^ swz;
            bf16x8 pa0 = *(const bf16x8*)((char*)Plds + pbase + (unsigned)fr * 128 + ro);
            bf16x8 pa1 = *(const bf16x8*)((char*)Plds + pbase + (unsigned)(16 + fr) * 128 + ro);
#pragma unroll
            for (int dt = 0; dt < 4; ++dt) {
                bf16x8 vf = *(const bf16x8*)(vtb + (size_t)(dt * 16 + fr) * 2048 + kb + kc * 32 + fg * 8);
                opv[0][dt] = __builtin_amdgcn_mfma_f32_16x16x32_bf16(pa0, vf, opv[0][dt], 0, 0, 0);
                opv[1][dt] = __builtin_amdgcn_mfma_f32_16x16x32_bf16(pa1, vf, opv[1][dt], 0, 0, 0);
            }
        }
    }

    __syncthreads();
    float* ored = (float*)Plds;  // [32][68], aliases P tiles (all PV reads done)
    for (int i = t; i < 32 * 68; i += 256) ored[i] = 0.f;
    __syncthreads();
    for (int ww = 0; ww < 4; ++ww) {
        if (w == ww) {
#pragma unroll
            for (int qs = 0; qs < 2; qs++)
#pragma unroll
                for (int dt = 0; dt < 4; dt++)
#pragma unroll
                    for (int r = 0; r < 4; r++)
                        ored[(qs * 16 + fg * 4 + r) * 68 + dt * 16 + fr] += opv[qs][dt][r];
        }
        __syncthreads();
    }
    {
        const int row = t >> 3, cb = (t & 7) * 8;
        ushort8 pk;
#pragma unroll
        for (int j = 0; j < 8; j++) pk[j] = f2bf(ored[row * 68 + cb + j]);
        *(ushort8*)(Obuf + (size_t)(b * 2048 + q0 + row) * 1024 + h * 64 + cb) = pk;
    }
}

extern "C" void kernel_launch(void* const* d_in, const int* in_sizes, int n_in,
                              void* d_out, int out_size, void* d_ws, size_t ws_size,
                              hipStream_t stream) {
    const float* q = (const float*)d_in[0];
    const float* k = (const float*)d_in[1];
    const float* v = (const float*)d_in[2];
    const float* wqw = (const float*)d_in[3];
    const float* wqb = (const float*)d_in[4];
    const float* wkw = (const float*)d_in[5];
    const float* wkb = (const float*)d_in[6];
    const float* wvw = (const float*)d_in[7];
    const float* wvb = (const float*)d_in[8];
    const float* wow = (const float*)d_in[9];
    const float* wob = (const float*)d_in[10];

    char* ws = (char*)d_ws;
    unsigned short* xbf  = (unsigned short*)(ws);              // 8 MB staging (reused q,k,v)
    unsigned short* wbf  = (unsigned short*)(ws + 8388608);    // 2 MB weight staging (reused)
    unsigned short* qh   = (unsigned short*)(ws + 10485760);   // [B,NH,S,HD] bf16
    unsigned short* kh   = (unsigned short*)(ws + 18874368);   // [B,NH,S,HD] bf16
    unsigned short* vt   = (unsigned short*)(ws + 27262976);   // [B,NH,HD,S] bf16
    unsigned short* obuf = (unsigned short*)(ws + 35651584);   // [B*S,H] bf16

    float* finalOut = (float*)d_out;
    float* attnOut = finalOut + 4194304;

    const int NX = 4194304, NW = 1048576;
    dim3 gGrid(8, 32), aGrid(64, 16, 2);

    cvt_kernel<<<NX / 1024, 256, 0, stream>>>(q, xbf, NX);
    cvt_kernel<<<NW / 1024, 256, 0, stream>>>(wqw, wbf, NW);
    gemm_bt<0><<<gGrid, 256, 0, stream>>>(xbf, wbf, wqb, qh);

    cvt_kernel<<<NX / 1024, 256, 0, stream>>>(k, xbf, NX);
    cvt_kernel<<<NW / 1024, 256, 0, stream>>>(wkw, wbf, NW);
    gemm_bt<0><<<gGrid, 256, 0, stream>>>(xbf, wbf, wkb, kh);

    cvt_kernel<<<NX / 1024, 256, 0, stream>>>(v, xbf, NX);
    cvt_kernel<<<NW / 1024, 256, 0, stream>>>(wvw, wbf, NW);
    gemm_bt<2><<<gGrid, 256, 0, stream>>>(xbf, wbf, wvb, vt);

    attn_kernel<<<aGrid, 256, 0, stream>>>(qh, kh, vt, obuf, attnOut);

    cvt_kernel<<<NW / 1024, 256, 0, stream>>>(wow, wbf, NW);
    gemm_bt<1><<<gGrid, 256, 0, stream>>>(obuf, wbf, wob, finalOut);
}

// Round 3
// 340.676 us; speedup vs baseline: 1.2663x; 1.0069x over previous
//
#include <hip/hip_runtime.h>

typedef short bf16x8 __attribute__((ext_vector_type(8)));      // 8 bf16 in 4 VGPRs
typedef float f32x4 __attribute__((ext_vector_type(4)));
typedef unsigned short ushort4v __attribute__((ext_vector_type(4)));
typedef unsigned short ushort8 __attribute__((ext_vector_type(8)));

#define DEVI static __device__ __forceinline__

DEVI unsigned short f2bf(float f) {               // RTNE fp32 -> bf16
    unsigned u = __float_as_uint(f);
    u += 0x7FFFu + ((u >> 16) & 1u);
    return (unsigned short)(u >> 16);
}

typedef __attribute__((address_space(3))) unsigned int* lds_ptr_t;
typedef const __attribute__((address_space(1))) unsigned int* gbl_ptr_t;
#define GLDS(gp, lp) __builtin_amdgcn_global_load_lds((gbl_ptr_t)(gp), (lds_ptr_t)(lp), 16, 0, 0)

// ---------------- fp32 -> bf16 converts ----------------
__global__ void cvt_kernel(const float* __restrict__ src, unsigned short* __restrict__ dst, int n) {
    int i = (blockIdx.x * 256 + threadIdx.x) * 4;
    if (i >= n) return;
    float4 v = *(const float4*)(src + i);
    ushort4v o;
    o.x = f2bf(v.x); o.y = f2bf(v.y); o.z = f2bf(v.z); o.w = f2bf(v.w);
    *(ushort4v*)(dst + i) = o;
}

// two segments in one launch (input + its weight)
__global__ void cvt2_kernel(const float* __restrict__ s0, unsigned short* __restrict__ d0, int n0,
                            const float* __restrict__ s1, unsigned short* __restrict__ d1, int n1) {
    int idx = blockIdx.x * 256 + threadIdx.x;
    const int c0 = n0 >> 2;
    const float* src; unsigned short* dst; int i;
    if (idx < c0) { src = s0; dst = d0; i = idx * 4; }
    else {
        i = (idx - c0) * 4;
        if (i >= n1) return;
        src = s1; dst = d1;
    }
    float4 v = *(const float4*)(src + i);
    ushort4v o;
    o.x = f2bf(v.x); o.y = f2bf(v.y); o.z = f2bf(v.z); o.w = f2bf(v.w);
    *(ushort4v*)(dst + i) = o;
}

// ---------------- bf16 GEMM, C[m][n] = sum_k A[m][k]*W[n][k] + bias[n] ----------------
template <int MODE>
__global__ __launch_bounds__(256) void gemm_bt(const unsigned short* __restrict__ A,
                                               const unsigned short* __restrict__ Bw,
                                               const float* __restrict__ bias,
                                               void* __restrict__ Cout) {
    constexpr int K = 1024;
    __shared__ unsigned short As[128 * 32];
    __shared__ unsigned short Bs[128 * 32];
    const int t = threadIdx.x;
    const int w = t >> 6, l = t & 63;
    const int wr = w >> 1, wc = w & 1;
    const int fr = l & 15, fg = l >> 4;
    const int m0 = blockIdx.y * 128, n0 = blockIdx.x * 128;

    f32x4 acc[4][4] = {};

    const int c0 = t, c1 = 256 + t;
    const int r0 = c0 >> 2, q0off = (c0 & 3) * 8;
    const int r1 = c1 >> 2, q1off = (c1 & 3) * 8;

    for (int kb = 0; kb < K; kb += 32) {
        GLDS(A + (size_t)(m0 + r0) * K + kb + q0off, As + c0 * 8);
        GLDS(A + (size_t)(m0 + r1) * K + kb + q1off, As + c1 * 8);
        GLDS(Bw + (size_t)(n0 + r0) * K + kb + q0off, Bs + c0 * 8);
        GLDS(Bw + (size_t)(n0 + r1) * K + kb + q1off, Bs + c1 * 8);
        asm volatile("s_waitcnt vmcnt(0)" ::: "memory");
        __syncthreads();
        bf16x8 af[4], bfv[4];
#pragma unroll
        for (int mi = 0; mi < 4; mi++)
            af[mi] = *(const bf16x8*)(As + (wr * 64 + mi * 16 + fr) * 32 + fg * 8);
#pragma unroll
        for (int ni = 0; ni < 4; ni++)
            bfv[ni] = *(const bf16x8*)(Bs + (wc * 64 + ni * 16 + fr) * 32 + fg * 8);
#pragma unroll
        for (int mi = 0; mi < 4; mi++)
#pragma unroll
            for (int ni = 0; ni < 4; ni++)
                acc[mi][ni] = __builtin_amdgcn_mfma_f32_16x16x32_bf16(af[mi], bfv[ni], acc[mi][ni], 0, 0, 0);
        __syncthreads();
    }

#pragma unroll
    for (int ni = 0; ni < 4; ni++) {
        const int n = n0 + wc * 64 + ni * 16 + fr;
        const float bv = bias[n];
#pragma unroll
        for (int mi = 0; mi < 4; mi++) {
            const int mb = m0 + wr * 64 + mi * 16 + fg * 4;
            if constexpr (MODE == 1) {
                float* C = (float*)Cout;
#pragma unroll
                for (int r = 0; r < 4; r++) C[(size_t)(mb + r) * 1024 + n] = acc[mi][ni][r] + bv;
            } else if constexpr (MODE == 0) {
                unsigned short* C = (unsigned short*)Cout;
                const int h = n >> 6, hd = n & 63;
#pragma unroll
                for (int r = 0; r < 4; r++) {
                    const int m = mb + r;
                    const int bb = m >> 11, s = m & 2047;
                    C[(size_t)((bb * 16 + h) * 2048 + s) * 64 + hd] = f2bf(acc[mi][ni][r] + bv);
                }
            } else {
                unsigned short* C = (unsigned short*)Cout;
                const int h = n >> 6, hd = n & 63;
                const int bb = mb >> 11, s = mb & 2047;
                ushort4v pk;
                pk.x = f2bf(acc[mi][ni][0] + bv);
                pk.y = f2bf(acc[mi][ni][1] + bv);
                pk.z = f2bf(acc[mi][ni][2] + bv);
                pk.w = f2bf(acc[mi][ni][3] + bv);
                *(ushort4v*)(C + (size_t)((bb * 16 + h) * 64 + hd) * 2048 + s) = pk;
            }
        }
    }
}

// ---------------- fused attention v3: two-pass, Pass B software-pipelined ----------------
// Block = 32 q rows of one (b,h); 4 waves, wave w owns k in [w*512,(w+1)*512).
// Pass B: stage(kt) = QK^T+exp+attn fp32 store+LDS pack (buf kt&1), overlapped with pv(kt-1)
// reading the other buffer. No inline-asm fences — compiler emits counted lgkmcnt.
__global__ __launch_bounds__(256, 4) void attn_kernel(const unsigned short* __restrict__ Qh,
                                                      const unsigned short* __restrict__ Kh,
                                                      const unsigned short* __restrict__ Vt,
                                                      unsigned short* __restrict__ Obuf,
                                                      float* __restrict__ AttnOut) {
    __shared__ char Plds[32768];  // 2 bufs x 4 waves x 4KB P-tiles [32q][64k] bf16, XOR-swizzled
    __shared__ float rpart[32][4];
    __shared__ float rinv_s[32];

    const int qt = blockIdx.x, h = blockIdx.y, b = blockIdx.z;
    const int bh = b * 16 + h;
    const int q0 = qt * 32;
    const int t = threadIdx.x, w = t >> 6, l = t & 63;
    const int fr = l & 15, fg = l >> 4;
    const unsigned swz = (unsigned)((fr & 7) << 4);

    const unsigned short* qb = Qh + (size_t)(bh * 2048 + q0) * 64;
    bf16x8 qf[2][2];
#pragma unroll
    for (int qs = 0; qs < 2; qs++)
#pragma unroll
        for (int kc = 0; kc < 2; kc++)
            qf[qs][kc] = *(const bf16x8*)(qb + (size_t)(qs * 16 + fr) * 64 + kc * 32 + fg * 8);

    const unsigned short* kbase = Kh + (size_t)bh * 2048 * 64;
    const unsigned short* vtb = Vt + (size_t)bh * 64 * 2048;

    // ---- Pass A: row-sums of exp(s) ----
    float s0 = 0.f, s1 = 0.f;
    for (int kt = 0; kt < 8; ++kt) {
        const int kb = w * 512 + kt * 64;
#pragma unroll
        for (int mt = 0; mt < 4; ++mt) {
            const unsigned short* kr = kbase + (size_t)(kb + mt * 16 + fr) * 64 + fg * 8;
            bf16x8 kf0 = *(const bf16x8*)kr;
            bf16x8 kf1 = *(const bf16x8*)(kr + 32);
            f32x4 d0 = {}, d1 = {};
            d0 = __builtin_amdgcn_mfma_f32_16x16x32_bf16(kf0, qf[0][0], d0, 0, 0, 0);
            d0 = __builtin_amdgcn_mfma_f32_16x16x32_bf16(kf1, qf[0][1], d0, 0, 0, 0);
            d1 = __builtin_amdgcn_mfma_f32_16x16x32_bf16(kf0, qf[1][0], d1, 0, 0, 0);
            d1 = __builtin_amdgcn_mfma_f32_16x16x32_bf16(kf1, qf[1][1], d1, 0, 0, 0);
#pragma unroll
            for (int r = 0; r < 4; r++) {
                s0 += __expf(d0[r] * 0.125f);
                s1 += __expf(d1[r] * 0.125f);
            }
        }
    }
    s0 += __shfl_xor(s0, 16, 64); s0 += __shfl_xor(s0, 32, 64);
    s1 += __shfl_xor(s1, 16, 64); s1 += __shfl_xor(s1, 32, 64);
    if (l < 16) { rpart[l][w] = s0; rpart[l + 16][w] = s1; }
    __syncthreads();
    if (t < 32) rinv_s[t] = 1.0f / (rpart[t][0] + rpart[t][1] + rpart[t][2] + rpart[t][3]);
    __syncthreads();
    const float ri0 = rinv_s[fr], ri1 = rinv_s[16 + fr];

    // ---- Pass B: pipelined stage/pv ----
    f32x4 opv[2][4] = {};
    float* attnB = AttnOut + (size_t)bh * 2048 * 2048;

#define STAGE(KT)                                                                                   \
    {                                                                                               \
        const int kb = w * 512 + (KT) * 64;                                                         \
        const unsigned pbase = (unsigned)((w + ((KT) & 1) * 4) * 4096);                             \
        _Pragma("unroll") for (int mt = 0; mt < 4; ++mt) {                                          \
            const unsigned short* kr = kbase + (size_t)(kb + mt * 16 + fr) * 64 + fg * 8;           \
            bf16x8 kf0 = *(const bf16x8*)kr;                                                        \
            bf16x8 kf1 = *(const bf16x8*)(kr + 32);                                                 \
            f32x4 d0 = {}, d1 = {};                                                                 \
            d0 = __builtin_amdgcn_mfma_f32_16x16x32_bf16(kf0, qf[0][0], d0, 0, 0, 0);               \
            d0 = __builtin_amdgcn_mfma_f32_16x16x32_bf16(kf1, qf[0][1], d0, 0, 0, 0);               \
            d1 = __builtin_amdgcn_mfma_f32_16x16x32_bf16(kf0, qf[1][0], d1, 0, 0, 0);               \
            d1 = __builtin_amdgcn_mfma_f32_16x16x32_bf16(kf1, qf[1][1], d1, 0, 0, 0);               \
            f32x4 p0, p1;                                                                           \
            _Pragma("unroll") for (int r = 0; r < 4; r++) {                                         \
                p0[r] = __expf(d0[r] * 0.125f) * ri0;                                               \
                p1[r] = __expf(d1[r] * 0.125f) * ri1;                                               \
            }                                                                                       \
            const int kcol = kb + mt * 16 + fg * 4;                                                 \
            __builtin_nontemporal_store(p0, (f32x4*)(attnB + (size_t)(q0 + fr) * 2048 + kcol));     \
            __builtin_nontemporal_store(p1, (f32x4*)(attnB + (size_t)(q0 + 16 + fr) * 2048 + kcol));\
            ushort4v pk0, pk1;                                                                      \
            _Pragma("unroll") for (int r = 0; r < 4; r++) { pk0[r] = f2bf(p0[r]); pk1[r] = f2bf(p1[r]); } \
            const unsigned colb = (unsigned)(mt * 32 + fg * 8) ^ swz;                               \
            *(ushort4v*)(Plds + pbase + (unsigned)fr * 128 + colb) = pk0;                           \
            *(ushort4v*)(Plds + pbase + (unsigned)(16 + fr) * 128 + colb) = pk1;                    \
        }                                                                                           \
    }

#define PVSTEP(KT)                                                                                  \
    {                                                                                               \
        const int kb = w * 512 + (KT) * 64;                                                         \
        const unsigned pbase = (unsigned)((w + ((KT) & 1) * 4) * 4096);                             \
        _Pragma("unroll") for (int kc = 0; kc < 2; ++kc) {                                          \
            const unsigned ro = (unsigned)(kc * 64 + fg * 16) ^ swz;                                \
            bf16x8 pa0 = *(const bf16x8*)(Plds + pbase + (unsigned)fr * 128 + ro);                  \
            bf16x8 pa1 = *(const bf16x8*)(Plds + pbase + (unsigned)(16 + fr) * 128 + ro);           \
            _Pragma("unroll") for (int dt = 0; dt < 4; ++dt) {                                      \
                bf16x8 vf = *(const bf16x8*)(vtb + (size_t)(dt * 16 + fr) * 2048 + kb + kc * 32 + fg * 8); \
                opv[0][dt] = __builtin_amdgcn_mfma_f32_16x16x32_bf16(pa0, vf, opv[0][dt], 0, 0, 0); \
                opv[1][dt] = __builtin_amdgcn_mfma_f32_16x16x32_bf16(pa1, vf, opv[1][dt], 0, 0, 0); \
            }                                                                                       \
        }                                                                                           \
    }

    STAGE(0);
    for (int kt = 1; kt < 8; ++kt) {
        STAGE(kt);
        PVSTEP(kt - 1);
    }
    PVSTEP(7);
#undef STAGE
#undef PVSTEP

    __syncthreads();
    float* ored = (float*)Plds;  // [32][68], aliases P tiles (all PV reads done)
    for (int i = t; i < 32 * 68; i += 256) ored[i] = 0.f;
    __syncthreads();
    for (int ww = 0; ww < 4; ++ww) {
        if (w == ww) {
#pragma unroll
            for (int qs = 0; qs < 2; qs++)
#pragma unroll
                for (int dt = 0; dt < 4; dt++)
#pragma unroll
                    for (int r = 0; r < 4; r++)
                        ored[(qs * 16 + fg * 4 + r) * 68 + dt * 16 + fr] += opv[qs][dt][r];
        }
        __syncthreads();
    }
    {
        const int row = t >> 3, cb = (t & 7) * 8;
        ushort8 pk;
#pragma unroll
        for (int j = 0; j < 8; j++) pk[j] = f2bf(ored[row * 68 + cb + j]);
        *(ushort8*)(Obuf + (size_t)(b * 2048 + q0 + row) * 1024 + h * 64 + cb) = pk;
    }
}

extern "C" void kernel_launch(void* const* d_in, const int* in_sizes, int n_in,
                              void* d_out, int out_size, void* d_ws, size_t ws_size,
                              hipStream_t stream) {
    const float* q = (const float*)d_in[0];
    const float* k = (const float*)d_in[1];
    const float* v = (const float*)d_in[2];
    const float* wqw = (const float*)d_in[3];
    const float* wqb = (const float*)d_in[4];
    const float* wkw = (const float*)d_in[5];
    const float* wkb = (const float*)d_in[6];
    const float* wvw = (const float*)d_in[7];
    const float* wvb = (const float*)d_in[8];
    const float* wow = (const float*)d_in[9];
    const float* wob = (const float*)d_in[10];

    char* ws = (char*)d_ws;
    unsigned short* xbf  = (unsigned short*)(ws);              // 8 MB staging (reused q,k,v)
    unsigned short* wbf  = (unsigned short*)(ws + 8388608);    // 2 MB weight staging (reused)
    unsigned short* qh   = (unsigned short*)(ws + 10485760);   // [B,NH,S,HD] bf16
    unsigned short* kh   = (unsigned short*)(ws + 18874368);   // [B,NH,S,HD] bf16
    unsigned short* vt   = (unsigned short*)(ws + 27262976);   // [B,NH,HD,S] bf16
    unsigned short* obuf = (unsigned short*)(ws + 35651584);   // [B*S,H] bf16

    float* finalOut = (float*)d_out;
    float* attnOut = finalOut + 4194304;

    const int NX = 4194304, NW = 1048576;
    const int c2grid = (NX + NW) / 1024;
    dim3 gGrid(8, 32), aGrid(64, 16, 2);

    cvt2_kernel<<<c2grid, 256, 0, stream>>>(q, xbf, NX, wqw, wbf, NW);
    gemm_bt<0><<<gGrid, 256, 0, stream>>>(xbf, wbf, wqb, qh);

    cvt2_kernel<<<c2grid, 256, 0, stream>>>(k, xbf, NX, wkw, wbf, NW);
    gemm_bt<0><<<gGrid, 256, 0, stream>>>(xbf, wbf, wkb, kh);

    cvt2_kernel<<<c2grid, 256, 0, stream>>>(v, xbf, NX, wvw, wbf, NW);
    gemm_bt<2><<<gGrid, 256, 0, stream>>>(xbf, wbf, wvb, vt);

    attn_kernel<<<aGrid, 256, 0, stream>>>(qh, kh, vt, obuf, attnOut);

    cvt_kernel<<<NW / 1024, 256, 0, stream>>>(wow, wbf, NW);
    gemm_bt<1><<<gGrid, 256, 0, stream>>>(obuf, wbf, wob, finalOut);
}

// Round 4
// 331.967 us; speedup vs baseline: 1.2995x; 1.0262x over previous
//
#include <hip/hip_runtime.h>

typedef short bf16x8 __attribute__((ext_vector_type(8)));      // 8 bf16 in 4 VGPRs
typedef float f32x4 __attribute__((ext_vector_type(4)));
typedef unsigned short ushort4v __attribute__((ext_vector_type(4)));
typedef unsigned short ushort8 __attribute__((ext_vector_type(8)));

#define DEVI static __device__ __forceinline__

DEVI unsigned short f2bf(float f) {               // RTNE fp32 -> bf16
    unsigned u = __float_as_uint(f);
    u += 0x7FFFu + ((u >> 16) & 1u);
    return (unsigned short)(u >> 16);
}

typedef __attribute__((address_space(3))) unsigned int* lds_ptr_t;
typedef const __attribute__((address_space(1))) unsigned int* gbl_ptr_t;
#define GLDS(gp, lp) __builtin_amdgcn_global_load_lds((gbl_ptr_t)(gp), (lds_ptr_t)(lp), 16, 0, 0)

// ---------------- fp32 -> bf16 converts ----------------
__global__ void cvt_kernel(const float* __restrict__ src, unsigned short* __restrict__ dst, int n) {
    int i = (blockIdx.x * 256 + threadIdx.x) * 4;
    if (i >= n) return;
    float4 v = *(const float4*)(src + i);
    ushort4v o;
    o.x = f2bf(v.x); o.y = f2bf(v.y); o.z = f2bf(v.z); o.w = f2bf(v.w);
    *(ushort4v*)(dst + i) = o;
}

// two segments in one launch (input + its weight)
__global__ void cvt2_kernel(const float* __restrict__ s0, unsigned short* __restrict__ d0, int n0,
                            const float* __restrict__ s1, unsigned short* __restrict__ d1, int n1) {
    int idx = blockIdx.x * 256 + threadIdx.x;
    const int c0 = n0 >> 2;
    const float* src; unsigned short* dst; int i;
    if (idx < c0) { src = s0; dst = d0; i = idx * 4; }
    else {
        i = (idx - c0) * 4;
        if (i >= n1) return;
        src = s1; dst = d1;
    }
    float4 v = *(const float4*)(src + i);
    ushort4v o;
    o.x = f2bf(v.x); o.y = f2bf(v.y); o.z = f2bf(v.z); o.w = f2bf(v.w);
    *(ushort4v*)(dst + i) = o;
}

// ---------------- bf16 GEMM v2: 64x128 tile, 2-phase prefetch, counted vmcnt ----------------
// C[m][n] = sum_k A[m][k]*W[n][k] + bias[n]. M=4096, N=1024, K=1024.
// grid (8, 64) = 512 blocks (~2/CU). 4 waves as 2Mx2N; wave tile 32x64.
// MODE 0: bf16 out [B,NH,S,HD]; MODE 1: fp32 out [M,N]; MODE 2: bf16 out [B,NH,HD,S].
template <int MODE>
__global__ __launch_bounds__(256) void gemm_bt(const unsigned short* __restrict__ A,
                                               const unsigned short* __restrict__ W,
                                               const float* __restrict__ bias,
                                               void* __restrict__ Cout) {
    constexpr int K = 1024;
    __shared__ unsigned short Asb[2][64 * 32];
    __shared__ unsigned short Bsb[2][128 * 32];
    const int t = threadIdx.x;
    const int w = t >> 6, l = t & 63;
    const int wr = w >> 1, wc = w & 1;
    const int fr = l & 15, fg = l >> 4;
    const int m0 = blockIdx.y * 64, n0 = blockIdx.x * 128;

    // staging coords: A-tile 64x32 (1 load/thread), B-tile 128x32 (2 loads/thread)
    const int ra = t >> 2, qa = (t & 3) * 8;
    const int c1 = 256 + t, rb1 = c1 >> 2, qb1 = (c1 & 3) * 8;

    f32x4 acc[2][4] = {};

#define STG(kb, pb)                                                        \
    {                                                                      \
        GLDS(A + (size_t)(m0 + ra) * K + (kb) + qa, &Asb[pb][t * 8]);      \
        GLDS(W + (size_t)(n0 + ra) * K + (kb) + qa, &Bsb[pb][t * 8]);      \
        GLDS(W + (size_t)(n0 + rb1) * K + (kb) + qb1, &Bsb[pb][c1 * 8]);   \
    }

    STG(0, 0);
    for (int t2 = 0; t2 < 32; ++t2) {
        const int cur = t2 & 1;
        if (t2 < 31) {
            STG((t2 + 1) * 32, cur ^ 1);
            asm volatile("s_waitcnt vmcnt(3)" ::: "memory");  // leave next tile's 3 loads in flight
        } else {
            asm volatile("s_waitcnt vmcnt(0)" ::: "memory");
        }
        __syncthreads();
        bf16x8 af[2], bfv[4];
#pragma unroll
        for (int mi = 0; mi < 2; mi++)
            af[mi] = *(const bf16x8*)(&Asb[cur][(wr * 32 + mi * 16 + fr) * 32 + fg * 8]);
#pragma unroll
        for (int ni = 0; ni < 4; ni++)
            bfv[ni] = *(const bf16x8*)(&Bsb[cur][(wc * 64 + ni * 16 + fr) * 32 + fg * 8]);
#pragma unroll
        for (int mi = 0; mi < 2; mi++)
#pragma unroll
            for (int ni = 0; ni < 4; ni++)
                acc[mi][ni] = __builtin_amdgcn_mfma_f32_16x16x32_bf16(af[mi], bfv[ni], acc[mi][ni], 0, 0, 0);
        __syncthreads();
    }
#undef STG

    // Epilogue. D layout: col = lane&15 (n), row = (lane>>4)*4 + r (m)
#pragma unroll
    for (int ni = 0; ni < 4; ni++) {
        const int n = n0 + wc * 64 + ni * 16 + fr;
        const float bv = bias[n];
#pragma unroll
        for (int mi = 0; mi < 2; mi++) {
            const int mb = m0 + wr * 32 + mi * 16 + fg * 4;
            if constexpr (MODE == 1) {
                float* C = (float*)Cout;
#pragma unroll
                for (int r = 0; r < 4; r++) C[(size_t)(mb + r) * 1024 + n] = acc[mi][ni][r] + bv;
            } else if constexpr (MODE == 0) {
                unsigned short* C = (unsigned short*)Cout;
                const int h = n >> 6, hd = n & 63;
#pragma unroll
                for (int r = 0; r < 4; r++) {
                    const int m = mb + r;
                    const int bb = m >> 11, s = m & 2047;
                    C[(size_t)((bb * 16 + h) * 2048 + s) * 64 + hd] = f2bf(acc[mi][ni][r] + bv);
                }
            } else {  // MODE 2: vt[B,NH,HD,S]; 4 consecutive s per lane -> 8B packed store
                unsigned short* C = (unsigned short*)Cout;
                const int h = n >> 6, hd = n & 63;
                const int bb = mb >> 11, s = mb & 2047;
                ushort4v pk;
                pk.x = f2bf(acc[mi][ni][0] + bv);
                pk.y = f2bf(acc[mi][ni][1] + bv);
                pk.z = f2bf(acc[mi][ni][2] + bv);
                pk.w = f2bf(acc[mi][ni][3] + bv);
                *(ushort4v*)(C + (size_t)((bb * 16 + h) * 64 + hd) * 2048 + s) = pk;
            }
        }
    }
}

// ---------------- fused attention (unchanged from R3) ----------------
__global__ __launch_bounds__(256, 4) void attn_kernel(const unsigned short* __restrict__ Qh,
                                                      const unsigned short* __restrict__ Kh,
                                                      const unsigned short* __restrict__ Vt,
                                                      unsigned short* __restrict__ Obuf,
                                                      float* __restrict__ AttnOut) {
    __shared__ char Plds[32768];  // 2 bufs x 4 waves x 4KB P-tiles [32q][64k] bf16, XOR-swizzled
    __shared__ float rpart[32][4];
    __shared__ float rinv_s[32];

    const int qt = blockIdx.x, h = blockIdx.y, b = blockIdx.z;
    const int bh = b * 16 + h;
    const int q0 = qt * 32;
    const int t = threadIdx.x, w = t >> 6, l = t & 63;
    const int fr = l & 15, fg = l >> 4;
    const unsigned swz = (unsigned)((fr & 7) << 4);

    const unsigned short* qb = Qh + (size_t)(bh * 2048 + q0) * 64;
    bf16x8 qf[2][2];
#pragma unroll
    for (int qs = 0; qs < 2; qs++)
#pragma unroll
        for (int kc = 0; kc < 2; kc++)
            qf[qs][kc] = *(const bf16x8*)(qb + (size_t)(qs * 16 + fr) * 64 + kc * 32 + fg * 8);

    const unsigned short* kbase = Kh + (size_t)bh * 2048 * 64;
    const unsigned short* vtb = Vt + (size_t)bh * 64 * 2048;

    // ---- Pass A: row-sums of exp(s) ----
    float s0 = 0.f, s1 = 0.f;
    for (int kt = 0; kt < 8; ++kt) {
        const int kb = w * 512 + kt * 64;
#pragma unroll
        for (int mt = 0; mt < 4; ++mt) {
            const unsigned short* kr = kbase + (size_t)(kb + mt * 16 + fr) * 64 + fg * 8;
            bf16x8 kf0 = *(const bf16x8*)kr;
            bf16x8 kf1 = *(const bf16x8*)(kr + 32);
            f32x4 d0 = {}, d1 = {};
            d0 = __builtin_amdgcn_mfma_f32_16x16x32_bf16(kf0, qf[0][0], d0, 0, 0, 0);
            d0 = __builtin_amdgcn_mfma_f32_16x16x32_bf16(kf1, qf[0][1], d0, 0, 0, 0);
            d1 = __builtin_amdgcn_mfma_f32_16x16x32_bf16(kf0, qf[1][0], d1, 0, 0, 0);
            d1 = __builtin_amdgcn_mfma_f32_16x16x32_bf16(kf1, qf[1][1], d1, 0, 0, 0);
#pragma unroll
            for (int r = 0; r < 4; r++) {
                s0 += __expf(d0[r] * 0.125f);
                s1 += __expf(d1[r] * 0.125f);
            }
        }
    }
    s0 += __shfl_xor(s0, 16, 64); s0 += __shfl_xor(s0, 32, 64);
    s1 += __shfl_xor(s1, 16, 64); s1 += __shfl_xor(s1, 32, 64);
    if (l < 16) { rpart[l][w] = s0; rpart[l + 16][w] = s1; }
    __syncthreads();
    if (t < 32) rinv_s[t] = 1.0f / (rpart[t][0] + rpart[t][1] + rpart[t][2] + rpart[t][3]);
    __syncthreads();
    const float ri0 = rinv_s[fr], ri1 = rinv_s[16 + fr];

    // ---- Pass B: pipelined stage/pv ----
    f32x4 opv[2][4] = {};
    float* attnB = AttnOut + (size_t)bh * 2048 * 2048;

#define STAGE(KT)                                                                                   \
    {                                                                                               \
        const int kb = w * 512 + (KT) * 64;                                                         \
        const unsigned pbase = (unsigned)((w + ((KT) & 1) * 4) * 4096);                             \
        _Pragma("unroll") for (int mt = 0; mt < 4; ++mt) {                                          \
            const unsigned short* kr = kbase + (size_t)(kb + mt * 16 + fr) * 64 + fg * 8;           \
            bf16x8 kf0 = *(const bf16x8*)kr;                                                        \
            bf16x8 kf1 = *(const bf16x8*)(kr + 32);                                                 \
            f32x4 d0 = {}, d1 = {};                                                                 \
            d0 = __builtin_amdgcn_mfma_f32_16x16x32_bf16(kf0, qf[0][0], d0, 0, 0, 0);               \
            d0 = __builtin_amdgcn_mfma_f32_16x16x32_bf16(kf1, qf[0][1], d0, 0, 0, 0);               \
            d1 = __builtin_amdgcn_mfma_f32_16x16x32_bf16(kf0, qf[1][0], d1, 0, 0, 0);               \
            d1 = __builtin_amdgcn_mfma_f32_16x16x32_bf16(kf1, qf[1][1], d1, 0, 0, 0);               \
            f32x4 p0, p1;                                                                           \
            _Pragma("unroll") for (int r = 0; r < 4; r++) {                                         \
                p0[r] = __expf(d0[r] * 0.125f) * ri0;                                               \
                p1[r] = __expf(d1[r] * 0.125f) * ri1;                                               \
            }                                                                                       \
            const int kcol = kb + mt * 16 + fg * 4;                                                 \
            __builtin_nontemporal_store(p0, (f32x4*)(attnB + (size_t)(q0 + fr) * 2048 + kcol));     \
            __builtin_nontemporal_store(p1, (f32x4*)(attnB + (size_t)(q0 + 16 + fr) * 2048 + kcol));\
            ushort4v pk0, pk1;                                                                      \
            _Pragma("unroll") for (int r = 0; r < 4; r++) { pk0[r] = f2bf(p0[r]); pk1[r] = f2bf(p1[r]); } \
            const unsigned colb = (unsigned)(mt * 32 + fg * 8) ^ swz;                               \
            *(ushort4v*)(Plds + pbase + (unsigned)fr * 128 + colb) = pk0;                           \
            *(ushort4v*)(Plds + pbase + (unsigned)(16 + fr) * 128 + colb) = pk1;                    \
        }                                                                                           \
    }

#define PVSTEP(KT)                                                                                  \
    {                                                                                               \
        const int kb = w * 512 + (KT) * 64;                                                         \
        const unsigned pbase = (unsigned)((w + ((KT) & 1) * 4) * 4096);                             \
        _Pragma("unroll") for (int kc = 0; kc < 2; ++kc) {                                          \
            const unsigned ro = (unsigned)(kc * 64 + fg * 16) ^ swz;                                \
            bf16x8 pa0 = *(const bf16x8*)(Plds + pbase + (unsigned)fr * 128 + ro);                  \
            bf16x8 pa1 = *(const bf16x8*)(Plds + pbase + (unsigned)(16 + fr) * 128 + ro);           \
            _Pragma("unroll") for (int dt = 0; dt < 4; ++dt) {                                      \
                bf16x8 vf = *(const bf16x8*)(vtb + (size_t)(dt * 16 + fr) * 2048 + kb + kc * 32 + fg * 8); \
                opv[0][dt] = __builtin_amdgcn_mfma_f32_16x16x32_bf16(pa0, vf, opv[0][dt], 0, 0, 0); \
                opv[1][dt] = __builtin_amdgcn_mfma_f32_16x16x32_bf16(pa1, vf, opv[1][dt], 0, 0, 0); \
            }                                                                                       \
        }                                                                                           \
    }

    STAGE(0);
    for (int kt = 1; kt < 8; ++kt) {
        STAGE(kt);
        PVSTEP(kt - 1);
    }
    PVSTEP(7);
#undef STAGE
#undef PVSTEP

    __syncthreads();
    float* ored = (float*)Plds;  // [32][68], aliases P tiles (all PV reads done)
    for (int i = t; i < 32 * 68; i += 256) ored[i] = 0.f;
    __syncthreads();
    for (int ww = 0; ww < 4; ++ww) {
        if (w == ww) {
#pragma unroll
            for (int qs = 0; qs < 2; qs++)
#pragma unroll
                for (int dt = 0; dt < 4; dt++)
#pragma unroll
                    for (int r = 0; r < 4; r++)
                        ored[(qs * 16 + fg * 4 + r) * 68 + dt * 16 + fr] += opv[qs][dt][r];
        }
        __syncthreads();
    }
    {
        const int row = t >> 3, cb = (t & 7) * 8;
        ushort8 pk;
#pragma unroll
        for (int j = 0; j < 8; j++) pk[j] = f2bf(ored[row * 68 + cb + j]);
        *(ushort8*)(Obuf + (size_t)(b * 2048 + q0 + row) * 1024 + h * 64 + cb) = pk;
    }
}

extern "C" void kernel_launch(void* const* d_in, const int* in_sizes, int n_in,
                              void* d_out, int out_size, void* d_ws, size_t ws_size,
                              hipStream_t stream) {
    const float* q = (const float*)d_in[0];
    const float* k = (const float*)d_in[1];
    const float* v = (const float*)d_in[2];
    const float* wqw = (const float*)d_in[3];
    const float* wqb = (const float*)d_in[4];
    const float* wkw = (const float*)d_in[5];
    const float* wkb = (const float*)d_in[6];
    const float* wvw = (const float*)d_in[7];
    const float* wvb = (const float*)d_in[8];
    const float* wow = (const float*)d_in[9];
    const float* wob = (const float*)d_in[10];

    char* ws = (char*)d_ws;
    unsigned short* xbf  = (unsigned short*)(ws);              // 8 MB staging (reused q,k,v)
    unsigned short* wbf  = (unsigned short*)(ws + 8388608);    // 2 MB weight staging (reused)
    unsigned short* qh   = (unsigned short*)(ws + 10485760);   // [B,NH,S,HD] bf16
    unsigned short* kh   = (unsigned short*)(ws + 18874368);   // [B,NH,S,HD] bf16
    unsigned short* vt   = (unsigned short*)(ws + 27262976);   // [B,NH,HD,S] bf16
    unsigned short* obuf = (unsigned short*)(ws + 35651584);   // [B*S,H] bf16

    float* finalOut = (float*)d_out;
    float* attnOut = finalOut + 4194304;

    const int NX = 4194304, NW = 1048576;
    const int c2grid = (NX + NW) / 1024;
    dim3 gGrid(8, 64), aGrid(64, 16, 2);

    cvt2_kernel<<<c2grid, 256, 0, stream>>>(q, xbf, NX, wqw, wbf, NW);
    gemm_bt<0><<<gGrid, 256, 0, stream>>>(xbf, wbf, wqb, qh);

    cvt2_kernel<<<c2grid, 256, 0, stream>>>(k, xbf, NX, wkw, wbf, NW);
    gemm_bt<0><<<gGrid, 256, 0, stream>>>(xbf, wbf, wkb, kh);

    cvt2_kernel<<<c2grid, 256, 0, stream>>>(v, xbf, NX, wvw, wbf, NW);
    gemm_bt<2><<<gGrid, 256, 0, stream>>>(xbf, wbf, wvb, vt);

    attn_kernel<<<aGrid, 256, 0, stream>>>(qh, kh, vt, obuf, attnOut);

    cvt_kernel<<<NW / 1024, 256, 0, stream>>>(wow, wbf, NW);
    gemm_bt<1><<<gGrid, 256, 0, stream>>>(obuf, wbf, wob, finalOut);
}